// Round 3
// baseline (300.199 us; speedup 1.0000x reference)
//
#include <hip/hip_runtime.h>
#include <math.h>

#define NN 50000
#define NE 3200000

#define NT    98         // dst tiles of 512 nodes: 98*512 = 50176 >= NN
#define TSZ   512
#define CAP   34816      // bucket capacity per tile (mean 32653, 12 sigma margin)
#define SCB   250        // scatter blocks
#define SCH   12800      // edges per scatter block (50 rounds x 256)
#define SROUNDS 50
#define STCAP 320        // LDS stage capacity per tile (63 leftover + 256 inserts)
#define NSL   8          // agg slices per tile -> 98*8 = 784 blocks

static constexpr float ACC_SCALE   = 0.005f;
static constexpr float MAX_VEL     = 0.02f;
static constexpr float NOISE_SCALE = 0.004f;
static constexpr float RADIUS      = 0.05f;

// d_out layout (float32): new_x[N*10], keep[N], scalars[7]
#define OUT_KEEP   500000
#define OUT_SCAL   550000
// scalars: 0,1 velocity_bonus; 2 border_cost; 3 food_reward; 4 dead_cost;
//          5 visible_food; 6 mean_food_dist

// ws layout (float units):
#define WS_NI    0          // float4[50176]              -> 200704 floats
#define WS_S2    200704     // float[50176*16]            -> ends 1003520
#define WS_GCUR  1003520    // int[NT] (pad to 128)       -> ends 1003648
#define WS_BK    1003648    // uint[NT*CAP = 3411968]     -> ends 4415616
#define WS_PACC  4415616    // float4[NSL*50176] = 1605632 floats -> ends 6021248
#define WS_PDEG  6021248    // int[NSL*50176 = 401408]    -> ends 6422656 (~25.7 MB)

// ---------------------------------------------------------------------------
// Kernel 1: per-node precompute.
//   s2[n][j] = b1[j] + cell[n]*W_edge[3][j] + sum_c x[n][c]*W_src[c][j]
// ---------------------------------------------------------------------------
__global__ __launch_bounds__(256) void k1_prep(
    const float* __restrict__ x,
    const float* __restrict__ W_edge,   // (4,16)
    const float* __restrict__ W_src,    // (10,16)
    const float* __restrict__ b1,       // (16,)
    float4* __restrict__ nodeinfo,
    float* __restrict__ s2,
    int* __restrict__ gcur,
    float* __restrict__ out_scalars)
{
    int n = blockIdx.x * 256 + threadIdx.x;
    if (blockIdx.x == 0) {
        if (threadIdx.x < 7) out_scalars[threadIdx.x] = 0.0f;
        if (threadIdx.x < NT) gcur[threadIdx.x] = threadIdx.x * CAP;
    }
    if (n >= NN) return;

    float xr[10];
#pragma unroll
    for (int c = 0; c < 10; ++c) xr[c] = x[n * 10 + c];
    float cell = xr[4];

    nodeinfo[n] = make_float4(xr[0], xr[1], cell, 0.0f);

#pragma unroll
    for (int j = 0; j < 16; ++j) {
        float v = fmaf(cell, W_edge[48 + j], b1[j]);
#pragma unroll
        for (int c = 0; c < 10; ++c) v = fmaf(xr[c], W_src[c * 16 + j], v);
        s2[n * 16 + j] = v;
    }
}

// ---------------------------------------------------------------------------
// Kernel 2: scatter edges into per-tile buckets, COALESCED.
// Per block: histogram -> one gcur atomic per tile (block-private region),
// then LDS-staged inserts flushed in 64-entry (256 B) coalesced chunks.
// Entry = src(16b) | dst_local(9b)<<16.
// ---------------------------------------------------------------------------
__global__ __launch_bounds__(256) void k_scatter(
    const int* __restrict__ src,
    const int* __restrict__ dst,
    int* __restrict__ gcur,
    unsigned* __restrict__ bucket)
{
    extern __shared__ unsigned smem[];
    unsigned* stage = smem;                       // NT*STCAP
    int* hist   = (int*)(smem + NT * STCAP);      // NT
    int* gbase  = hist  + NT;
    int* lofs   = gbase + NT;
    int* scnt   = lofs  + NT;
    int* wl_t   = scnt  + NT;
    int* wl_n   = wl_t  + NT;
    int* wl_g   = wl_n  + NT;
    int* wl_cnt = wl_g  + NT;

    int tid = threadIdx.x;
    for (int i = tid; i < NT; i += 256) { hist[i] = 0; lofs[i] = 0; scnt[i] = 0; }
    __syncthreads();

    int e0 = blockIdx.x * SCH;

    // phase 1: per-block histogram over dst
#pragma unroll 4
    for (int r = 0; r < SROUNDS; ++r) {
        int d = dst[e0 + r * 256 + tid];
        atomicAdd(&hist[d >> 9], 1);
    }
    __syncthreads();
    if (tid < NT) gbase[tid] = atomicAdd(&gcur[tid], hist[tid]);
    // (visible to all after the sync inside round 0)

    // phase 2: staged insert + chunk flush, depth-2 prefetch
    int eA = e0 + tid;
    int dA = dst[eA],        sA = src[eA];
    int dB = dst[eA + 256],  sB = src[eA + 256];

    for (int r = 0; r < SROUNDS; ++r) {
        int dc = dA, sc = sA;
        dA = dB; sA = sB;
        int en = eA + (r + 2) * 256;
        if (r + 2 < SROUNDS) { dB = dst[en]; sB = src[en]; }

        if (tid == 0) *wl_cnt = 0;
        {
            int t = dc >> 9;
            unsigned entry = (unsigned)sc | ((unsigned)(dc & 511) << 16);
            int pos = atomicAdd(&scnt[t], 1);
            stage[t * STCAP + pos] = entry;
        }
        __syncthreads();

        // build flush worklist (full 64-chunks only)
        if (tid < NT) {
            int c = scnt[tid];
            int nf = (c >> 6) << 6;
            if (nf) {
                int slot = atomicAdd(wl_cnt, 1);
                wl_t[slot] = tid;
                wl_n[slot] = nf;
                wl_g[slot] = gbase[tid] + lofs[tid];
                lofs[tid] += nf;
            }
        }
        __syncthreads();

        int nw = *wl_cnt;
        for (int w = 0; w < nw; ++w) {
            int t = wl_t[w], n = wl_n[w], g0 = wl_g[w];
            int glim = (t + 1) * CAP;
            for (int idx = tid; idx < n; idx += 256) {
                int g = g0 + idx;
                if (g < glim) bucket[g] = stage[t * STCAP + idx];
            }
        }
        __syncthreads();

        // compact leftovers to the front of each flushed tile's stage
        if (tid < nw) {
            int t = wl_t[tid], n = wl_n[tid];
            int c = scnt[t];
            for (int j = 0; j + n < c; ++j)
                stage[t * STCAP + j] = stage[t * STCAP + n + j];
            scnt[t] = c - n;
        }
        __syncthreads();
    }

    // drain remainders (< 64 per tile)
    if (tid == 0) *wl_cnt = 0;
    __syncthreads();
    if (tid < NT) {
        int c = scnt[tid];
        if (c) {
            int slot = atomicAdd(wl_cnt, 1);
            wl_t[slot] = tid;
            wl_n[slot] = c;
            wl_g[slot] = gbase[tid] + lofs[tid];
        }
    }
    __syncthreads();
    int nw = *wl_cnt;
    for (int w = 0; w < nw; ++w) {
        int t = wl_t[w], n = wl_n[w], g0 = wl_g[w];
        int glim = (t + 1) * CAP;
        for (int idx = tid; idx < n; idx += 256) {
            int g = g0 + idx;
            if (g < glim) bucket[g] = stage[t * STCAP + idx];
        }
    }
}

// ---------------------------------------------------------------------------
// Kernel 3: aggregation.  Block (t, sl) processes slice sl of tile t's bucket,
// accumulates into LDS, writes partial sums (no global atomics).
// ---------------------------------------------------------------------------
__global__ __launch_bounds__(256) void k_agg(
    const float* __restrict__ W_edge,   // (4,16)
    const float* __restrict__ W_out,    // (16,4)
    const float4* __restrict__ nodeinfo,
    const float* __restrict__ s2,
    const int* __restrict__ gcur,
    const unsigned* __restrict__ bucket,
    float4* __restrict__ pacc,
    int* __restrict__ pdeg,
    float* __restrict__ out_scalars)
{
    __shared__ float  sAcc[TSZ][4];
    __shared__ int    sDeg[TSZ];
    __shared__ float4 sNI[TSZ];
    __shared__ float  sRed[4][2];

    int t   = blockIdx.x >> 3;
    int sl  = blockIdx.x & 7;
    int tid = threadIdx.x;

    for (int j = tid; j < TSZ; j += 256) {
        int g = t * TSZ + j;
        sNI[j] = (g < NN) ? nodeinfo[g] : make_float4(9e9f, 9e9f, -1.f, 0.f);
        sAcc[j][0] = 0.f; sAcc[j][1] = 0.f; sAcc[j][2] = 0.f; sAcc[j][3] = 0.f;
        sDeg[j] = 0;
    }

    // weights are wave-uniform -> compiler hoists to SGPRs
    float w0[16], w1[16], w2[16], woa[16], wob[16], woc[16], wod[16];
#pragma unroll
    for (int k = 0; k < 16; ++k) {
        w0[k] = W_edge[k];
        w1[k] = W_edge[16 + k];
        w2[k] = W_edge[32 + k];
        woa[k] = W_out[k * 4 + 0];
        wob[k] = W_out[k * 4 + 1];
        woc[k] = W_out[k * 4 + 2];
        wod[k] = W_out[k * 4 + 3];
    }
    __syncthreads();

    int cnt = gcur[t] - t * CAP;
    if (cnt > CAP) cnt = CAP;
    int cs = (cnt + NSL - 1) / NSL;
    int i0 = sl * cs;
    int i1 = min(i0 + cs, cnt);

    float vis = 0.f, fd = 0.f;
#pragma unroll 2
    for (int i = i0 + tid; i < i1; i += 256) {
        unsigned e = bucket[t * CAP + i];
        int s  = e & 0xFFFF;
        int dl = (e >> 16) & 0x1FF;
        float4 ns = nodeinfo[s];
        float4 nt = sNI[dl];
        float dx = ns.x - nt.x;
        float dy = ns.y - nt.y;
        float dist = sqrtf(fmaf(dx, dx, fmaf(dy, dy, 1e-12f)));

        bool food0 = (ns.z == 0.0f);
        vis += food0 ? 1.f : 0.f;
        fd  += food0 ? dist : 0.f;

        bool consume = (dist < RADIUS) && (ns.z == 1.0f) && (nt.z == 0.0f);
        atomicAdd(&sDeg[dl], consume ? 65537 : 1);

        const float4* sv4 = (const float4*)(s2 + (size_t)s * 16);
        float4 q0 = sv4[0], q1 = sv4[1], q2 = sv4[2], q3 = sv4[3];
        float sv[16] = { q0.x, q0.y, q0.z, q0.w, q1.x, q1.y, q1.z, q1.w,
                         q2.x, q2.y, q2.z, q2.w, q3.x, q3.y, q3.z, q3.w };

        float v0 = 0.f, v1 = 0.f, v2 = 0.f, v3 = 0.f;
#pragma unroll
        for (int k = 0; k < 16; ++k) {
            float m = fmaf(dist, w0[k], fmaf(dx, w1[k], fmaf(dy, w2[k], sv[k])));
            m = fmaxf(m, 0.0f);
            v0 = fmaf(m, woa[k], v0);
            v1 = fmaf(m, wob[k], v1);
            v2 = fmaf(m, woc[k], v2);
            v3 = fmaf(m, wod[k], v3);
        }
        atomicAdd(&sAcc[dl][0], v0);
        atomicAdd(&sAcc[dl][1], v1);
        atomicAdd(&sAcc[dl][2], v2);
        atomicAdd(&sAcc[dl][3], v3);
    }
    __syncthreads();

    // write partials (coalesced)
    for (int j = tid; j < TSZ; j += 256) {
        int o = sl * (NT * TSZ) + t * TSZ + j;
        pacc[o] = make_float4(sAcc[j][0], sAcc[j][1], sAcc[j][2], sAcc[j][3]);
        pdeg[o] = sDeg[j];
    }

    // block-reduce vis/fd
#pragma unroll
    for (int off = 32; off > 0; off >>= 1) {
        vis += __shfl_down(vis, off);
        fd  += __shfl_down(fd,  off);
    }
    int lane = tid & 63, wv = tid >> 6;
    if (lane == 0) { sRed[wv][0] = vis; sRed[wv][1] = fd; }
    __syncthreads();
    if (tid == 0) {
        float a = 0.f, b = 0.f;
#pragma unroll
        for (int wq = 0; wq < 4; ++wq) { a += sRed[wq][0]; b += sRed[wq][1]; }
        atomicAdd(&out_scalars[5], a);
        atomicAdd(&out_scalars[6], b);
    }
}

// ---------------------------------------------------------------------------
// Kernel 4: merge partials + node finalize + scalar reductions.
// ---------------------------------------------------------------------------
__global__ __launch_bounds__(256) void k_final(
    const float* __restrict__ x,
    const float* __restrict__ noise,
    const float* __restrict__ b2,       // (4,)
    const float4* __restrict__ pacc,
    const int* __restrict__ pdeg,
    float* __restrict__ out,
    float* __restrict__ out_scalars)
{
    __shared__ float sRed[4][5];
    int n = blockIdx.x * 256 + threadIdx.x;   // grid 196*256 = 50176
    int tid = threadIdx.x;

    float avx = 0.f, avy = 0.f, bc = 0.f, deadf = 0.f, consf = 0.f;

    if (n < NN) {
        float a0 = 0.f, a1 = 0.f, a2 = 0.f, a3 = 0.f;
        int dp = 0;
#pragma unroll
        for (int sl = 0; sl < NSL; ++sl) {
            float4 q = pacc[sl * (NT * TSZ) + n];
            a0 += q.x; a1 += q.y; a2 += q.z; a3 += q.w;
            dp += pdeg[sl * (NT * TSZ) + n];
        }

        float cell = x[n * 10 + 4];
        float cm = (cell == 1.0f) ? 1.0f : 0.0f;
        float h0 = tanhf(a0 + b2[0]) * cm;
        float h1 = tanhf(a1 + b2[1]) * cm;
        float h2 = tanhf(a2 + b2[2]) * cm;
        float h3 = tanhf(a3 + b2[3]) * cm;

        float px = x[n * 10 + 0], py = x[n * 10 + 1];
        float vx = x[n * 10 + 2], vy = x[n * 10 + 3];

        float nvx = fminf(fmaxf(fmaf(h0, ACC_SCALE, vx), -MAX_VEL), MAX_VEL);
        float nvy = fminf(fmaxf(fmaf(h1, ACC_SCALE, vy), -MAX_VEL), MAX_VEL);
        float npx = px + nvx;
        float npy = py + nvy;

        float vnx = nvx + (noise[n * 2 + 0] * 2.0f - 1.0f) * NOISE_SCALE * cm;
        float vny = nvy + (noise[n * 2 + 1] * 2.0f - 1.0f) * NOISE_SCALE * cm;

        float* row = out + (size_t)n * 10;
        row[0] = npx;  row[1] = npy;
        row[2] = vnx;  row[3] = vny;
        row[4] = cell; row[5] = h2;  row[6] = h3;
        row[7] = x[n * 10 + 7];
        row[8] = x[n * 10 + 8];
        row[9] = x[n * 10 + 9];

        float apx = fabsf(npx), apy = fabsf(npy);
        if (apx > 1.0f) bc += logf(apx + 1e-6f);
        if (apy > 1.0f) bc += logf(apy + 1e-6f);

        int deg  = dp & 0xFFFF;
        int cdeg = dp >> 16;
        bool dead = (cell == 1.0f) && (deg < 3);
        bool cons = (cell == 0.0f) && (cdeg >= 3);
        out[OUT_KEEP + n] = (dead || cons) ? 0.0f : 1.0f;
        deadf = dead ? 1.0f : 0.0f;
        consf = cons ? 1.0f : 0.0f;
        avx = fabsf(nvx) * (1.0f / NN);
        avy = fabsf(nvy) * (1.0f / NN);
    }

    float r[5] = { avx, avy, bc, consf, deadf };
#pragma unroll
    for (int q = 0; q < 5; ++q) {
#pragma unroll
        for (int off = 32; off > 0; off >>= 1)
            r[q] += __shfl_down(r[q], off);
    }
    int lane = tid & 63, wv = tid >> 6;
    if (lane == 0) {
#pragma unroll
        for (int q = 0; q < 5; ++q) sRed[wv][q] = r[q];
    }
    __syncthreads();
    if (tid == 0) {
#pragma unroll
        for (int q = 0; q < 5; ++q) {
            float acc = sRed[0][q] + sRed[1][q] + sRed[2][q] + sRed[3][q];
            atomicAdd(&out_scalars[q], acc);
        }
    }
}

extern "C" void kernel_launch(void* const* d_in, const int* in_sizes, int n_in,
                              void* d_out, int out_size, void* d_ws, size_t ws_size,
                              hipStream_t stream) {
    const float* x      = (const float*)d_in[0];
    const int*   src    = (const int*)  d_in[1];
    const int*   dst    = (const int*)  d_in[2];
    const float* noise  = (const float*)d_in[3];
    const float* W_edge = (const float*)d_in[4];
    const float* W_src  = (const float*)d_in[5];
    const float* b1     = (const float*)d_in[6];
    const float* W_out  = (const float*)d_in[7];
    const float* b2     = (const float*)d_in[8];

    float* ws = (float*)d_ws;
    float4*   nodeinfo = (float4*)(ws + WS_NI);
    float*    s2       = ws + WS_S2;
    int*      gcur     = (int*)(ws + WS_GCUR);
    unsigned* bucket   = (unsigned*)(ws + WS_BK);
    float4*   pacc     = (float4*)(ws + WS_PACC);
    int*      pdeg     = (int*)(ws + WS_PDEG);

    float* out         = (float*)d_out;
    float* out_scalars = out + OUT_SCAL;

    k1_prep<<<196, 256, 0, stream>>>(
        x, W_edge, W_src, b1, nodeinfo, s2, gcur, out_scalars);

    size_t scatter_lds = (size_t)(NT * STCAP + 7 * NT + 1) * sizeof(unsigned);
    k_scatter<<<SCB, 256, scatter_lds, stream>>>(src, dst, gcur, bucket);

    k_agg<<<NT * NSL, 256, 0, stream>>>(
        W_edge, W_out, nodeinfo, s2, gcur, bucket, pacc, pdeg, out_scalars);

    k_final<<<196, 256, 0, stream>>>(
        x, noise, b2, pacc, pdeg, out, out_scalars);
}

// Round 4
// 220.323 us; speedup vs baseline: 1.3625x; 1.3625x over previous
//
#include <hip/hip_runtime.h>
#include <math.h>

#define NN 50000
#define NE 3200000

#define NT    98         // dst tiles of 512 nodes: 98*512 = 50176 >= NN
#define TSZ   512
#define CAP   34816      // bucket capacity per tile (mean 32653, ~12 sigma margin)
#define SCB   625        // scatter blocks
#define EPB   5120       // edges per scatter block
#define EPT   20         // edges per thread (EPB/256)
#define NSL   8          // agg slices per tile -> 98*8 = 784 blocks

static constexpr float ACC_SCALE   = 0.005f;
static constexpr float MAX_VEL     = 0.02f;
static constexpr float NOISE_SCALE = 0.004f;
static constexpr float RADIUS      = 0.05f;

// d_out layout (float32): new_x[N*10], keep[N], scalars[7]
#define OUT_KEEP   500000
#define OUT_SCAL   550000
// scalars: 0,1 velocity_bonus; 2 border_cost; 3 food_reward; 4 dead_cost;
//          5 visible_food; 6 mean_food_dist

// ws layout (float units):
#define WS_NI    0          // float4[50176]              -> 200704 floats
#define WS_S2    200704     // float[50176*16]            -> ends 1003520
#define WS_GCUR  1003520    // int[NT*16] padded, 1 tile per 64B line -> ends 1005120
#define WS_BK    1005120    // uint[NT*CAP = 3411968]     -> ends 4417088
#define WS_PACC  4417088    // float4[NSL*50176] = 1605632 floats -> ends 6022720
#define WS_PDEG  6022720    // int[NSL*50176 = 401408]    -> ends 6424128 (~25.7 MB)

// ---------------------------------------------------------------------------
// Kernel 1: per-node precompute.
//   s2[n][j] = b1[j] + cell[n]*W_edge[3][j] + sum_c x[n][c]*W_src[c][j]
// ---------------------------------------------------------------------------
__global__ __launch_bounds__(256) void k1_prep(
    const float* __restrict__ x,
    const float* __restrict__ W_edge,   // (4,16)
    const float* __restrict__ W_src,    // (10,16)
    const float* __restrict__ b1,       // (16,)
    float4* __restrict__ nodeinfo,
    float* __restrict__ s2,
    int* __restrict__ gcur,
    float* __restrict__ out_scalars)
{
    int n = blockIdx.x * 256 + threadIdx.x;
    if (blockIdx.x == 0) {
        if (threadIdx.x < 7) out_scalars[threadIdx.x] = 0.0f;
        for (int i = threadIdx.x; i < NT * 16; i += 256)
            gcur[i] = (i & 15) ? 0 : (i >> 4) * CAP;
    }
    if (n >= NN) return;

    float xr[10];
#pragma unroll
    for (int c = 0; c < 10; ++c) xr[c] = x[n * 10 + c];
    float cell = xr[4];

    nodeinfo[n] = make_float4(xr[0], xr[1], cell, 0.0f);

#pragma unroll
    for (int j = 0; j < 16; ++j) {
        float v = fmaf(cell, W_edge[48 + j], b1[j]);
#pragma unroll
        for (int c = 0; c < 10; ++c) v = fmaf(xr[c], W_src[c * 16 + j], v);
        s2[n * 16 + j] = v;
    }
}

// ---------------------------------------------------------------------------
// Kernel 2: per-block LDS counting sort of a 5120-edge chunk, then one
// coalesced streamed flush.  dst held in 20 registers (read once).
// Entry = src(16b) | dst_local(9b)<<16.
// ---------------------------------------------------------------------------
__global__ __launch_bounds__(256) void k_scatter(
    const int* __restrict__ src,
    const int* __restrict__ dst,
    int* __restrict__ gcur,
    unsigned* __restrict__ bucket)
{
    __shared__ unsigned      stage[EPB];     // 20.5 KB
    __shared__ unsigned char binid[EPB];     // 5 KB
    __shared__ int hist[NT], binstart[NT], lcur[NT], gbase[NT];
    __shared__ int scanbuf[128];

    int tid = threadIdx.x;
    for (int i = tid; i < NT; i += 256) { hist[i] = 0; lcur[i] = 0; }
    __syncthreads();

    int e0 = blockIdx.x * EPB;

    // phase 1: histogram; dst stays in registers (static-indexed via unroll)
    int d[EPT];
#pragma unroll
    for (int j = 0; j < EPT; ++j) d[j] = dst[e0 + j * 256 + tid];
#pragma unroll
    for (int j = 0; j < EPT; ++j) atomicAdd(&hist[d[j] >> 9], 1);
    __syncthreads();

    // phase 2: exclusive scan over 98 bins (Hillis-Steele, 128 wide)
    if (tid < 128) scanbuf[tid] = (tid < NT) ? hist[tid] : 0;
    __syncthreads();
    for (int off = 1; off < 128; off <<= 1) {
        int v = 0;
        if (tid < 128 && tid >= off) v = scanbuf[tid - off];
        __syncthreads();
        if (tid < 128) scanbuf[tid] += v;
        __syncthreads();
    }
    if (tid < NT) {
        binstart[tid] = scanbuf[tid] - hist[tid];
        gbase[tid] = atomicAdd(&gcur[tid * 16], hist[tid]);  // padded: 1 line/tile
    }
    __syncthreads();

    // phase 3: placement into sorted LDS stage
    int sreg[EPT];
#pragma unroll
    for (int j = 0; j < EPT; ++j) sreg[j] = src[e0 + j * 256 + tid];
#pragma unroll
    for (int j = 0; j < EPT; ++j) {
        int t = d[j] >> 9;
        int pos = binstart[t] + atomicAdd(&lcur[t], 1);
        stage[pos] = (unsigned)sreg[j] | ((unsigned)(d[j] & 511) << 16);
        binid[pos] = (unsigned char)t;
    }
    __syncthreads();

    // phase 4: coalesced flush (consecutive i in a bin -> consecutive g)
#pragma unroll
    for (int j = 0; j < EPT; ++j) {
        int i = j * 256 + tid;
        int b = binid[i];
        int g = gbase[b] + (i - binstart[b]);
        if (g < (b + 1) * CAP) bucket[g] = stage[i];
    }
}

// ---------------------------------------------------------------------------
// Kernel 3: aggregation.  Block (t, sl) processes slice sl of tile t's bucket,
// accumulates into LDS, writes partial sums (no global atomics).
// ---------------------------------------------------------------------------
__global__ __launch_bounds__(512) void k_agg(
    const float* __restrict__ W_edge,   // (4,16)
    const float* __restrict__ W_out,    // (16,4)
    const float4* __restrict__ nodeinfo,
    const float* __restrict__ s2,
    const int* __restrict__ gcur,
    const unsigned* __restrict__ bucket,
    float4* __restrict__ pacc,
    int* __restrict__ pdeg,
    float* __restrict__ out_scalars)
{
    __shared__ float  sAcc[TSZ][4];
    __shared__ int    sDeg[TSZ];
    __shared__ float4 sNI[TSZ];
    __shared__ float  sRed[8][2];

    int t   = blockIdx.x >> 3;
    int sl  = blockIdx.x & 7;
    int tid = threadIdx.x;

    for (int j = tid; j < TSZ; j += 512) {
        int g = t * TSZ + j;
        sNI[j] = (g < NN) ? nodeinfo[g] : make_float4(9e9f, 9e9f, -1.f, 0.f);
        sAcc[j][0] = 0.f; sAcc[j][1] = 0.f; sAcc[j][2] = 0.f; sAcc[j][3] = 0.f;
        sDeg[j] = 0;
    }

    // wave-uniform weights -> SGPRs
    float w0[16], w1[16], w2[16], woa[16], wob[16], woc[16], wod[16];
#pragma unroll
    for (int k = 0; k < 16; ++k) {
        w0[k] = W_edge[k];
        w1[k] = W_edge[16 + k];
        w2[k] = W_edge[32 + k];
        woa[k] = W_out[k * 4 + 0];
        wob[k] = W_out[k * 4 + 1];
        woc[k] = W_out[k * 4 + 2];
        wod[k] = W_out[k * 4 + 3];
    }
    __syncthreads();

    int cnt = gcur[t * 16] - t * CAP;
    if (cnt > CAP) cnt = CAP;
    int cs = (cnt + NSL - 1) / NSL;
    int i0 = sl * cs;
    int i1 = min(i0 + cs, cnt);

    float vis = 0.f, fd = 0.f;
#pragma unroll 2
    for (int i = i0 + tid; i < i1; i += 512) {
        unsigned e = bucket[t * CAP + i];
        int s  = e & 0xFFFF;
        int dl = (e >> 16) & 0x1FF;
        float4 ns = nodeinfo[s];
        float4 nt = sNI[dl];
        float dx = ns.x - nt.x;
        float dy = ns.y - nt.y;
        float dist = sqrtf(fmaf(dx, dx, fmaf(dy, dy, 1e-12f)));

        bool food0 = (ns.z == 0.0f);
        vis += food0 ? 1.f : 0.f;
        fd  += food0 ? dist : 0.f;

        bool consume = (dist < RADIUS) && (ns.z == 1.0f) && (nt.z == 0.0f);
        atomicAdd(&sDeg[dl], consume ? 65537 : 1);

        const float4* sv4 = (const float4*)(s2 + (size_t)s * 16);
        float4 q0 = sv4[0], q1 = sv4[1], q2 = sv4[2], q3 = sv4[3];
        float sv[16] = { q0.x, q0.y, q0.z, q0.w, q1.x, q1.y, q1.z, q1.w,
                         q2.x, q2.y, q2.z, q2.w, q3.x, q3.y, q3.z, q3.w };

        float v0 = 0.f, v1 = 0.f, v2 = 0.f, v3 = 0.f;
#pragma unroll
        for (int k = 0; k < 16; ++k) {
            float m = fmaf(dist, w0[k], fmaf(dx, w1[k], fmaf(dy, w2[k], sv[k])));
            m = fmaxf(m, 0.0f);
            v0 = fmaf(m, woa[k], v0);
            v1 = fmaf(m, wob[k], v1);
            v2 = fmaf(m, woc[k], v2);
            v3 = fmaf(m, wod[k], v3);
        }
        atomicAdd(&sAcc[dl][0], v0);
        atomicAdd(&sAcc[dl][1], v1);
        atomicAdd(&sAcc[dl][2], v2);
        atomicAdd(&sAcc[dl][3], v3);
    }
    __syncthreads();

    // write partials (coalesced)
    for (int j = tid; j < TSZ; j += 512) {
        int o = sl * (NT * TSZ) + t * TSZ + j;
        pacc[o] = make_float4(sAcc[j][0], sAcc[j][1], sAcc[j][2], sAcc[j][3]);
        pdeg[o] = sDeg[j];
    }

    // block-reduce vis/fd
#pragma unroll
    for (int off = 32; off > 0; off >>= 1) {
        vis += __shfl_down(vis, off);
        fd  += __shfl_down(fd,  off);
    }
    int lane = tid & 63, wv = tid >> 6;
    if (lane == 0) { sRed[wv][0] = vis; sRed[wv][1] = fd; }
    __syncthreads();
    if (tid == 0) {
        float a = 0.f, b = 0.f;
#pragma unroll
        for (int wq = 0; wq < 8; ++wq) { a += sRed[wq][0]; b += sRed[wq][1]; }
        atomicAdd(&out_scalars[5], a);
        atomicAdd(&out_scalars[6], b);
    }
}

// ---------------------------------------------------------------------------
// Kernel 4: merge partials + node finalize + scalar reductions.
// ---------------------------------------------------------------------------
__global__ __launch_bounds__(256) void k_final(
    const float* __restrict__ x,
    const float* __restrict__ noise,
    const float* __restrict__ b2,       // (4,)
    const float4* __restrict__ pacc,
    const int* __restrict__ pdeg,
    float* __restrict__ out,
    float* __restrict__ out_scalars)
{
    __shared__ float sRed[4][5];
    int n = blockIdx.x * 256 + threadIdx.x;   // grid 196*256 = 50176
    int tid = threadIdx.x;

    float avx = 0.f, avy = 0.f, bc = 0.f, deadf = 0.f, consf = 0.f;

    if (n < NN) {
        float a0 = 0.f, a1 = 0.f, a2 = 0.f, a3 = 0.f;
        int dp = 0;
#pragma unroll
        for (int sl = 0; sl < NSL; ++sl) {
            float4 q = pacc[sl * (NT * TSZ) + n];
            a0 += q.x; a1 += q.y; a2 += q.z; a3 += q.w;
            dp += pdeg[sl * (NT * TSZ) + n];
        }

        float cell = x[n * 10 + 4];
        float cm = (cell == 1.0f) ? 1.0f : 0.0f;
        float h0 = tanhf(a0 + b2[0]) * cm;
        float h1 = tanhf(a1 + b2[1]) * cm;
        float h2 = tanhf(a2 + b2[2]) * cm;
        float h3 = tanhf(a3 + b2[3]) * cm;

        float px = x[n * 10 + 0], py = x[n * 10 + 1];
        float vx = x[n * 10 + 2], vy = x[n * 10 + 3];

        float nvx = fminf(fmaxf(fmaf(h0, ACC_SCALE, vx), -MAX_VEL), MAX_VEL);
        float nvy = fminf(fmaxf(fmaf(h1, ACC_SCALE, vy), -MAX_VEL), MAX_VEL);
        float npx = px + nvx;
        float npy = py + nvy;

        float vnx = nvx + (noise[n * 2 + 0] * 2.0f - 1.0f) * NOISE_SCALE * cm;
        float vny = nvy + (noise[n * 2 + 1] * 2.0f - 1.0f) * NOISE_SCALE * cm;

        float* row = out + (size_t)n * 10;
        row[0] = npx;  row[1] = npy;
        row[2] = vnx;  row[3] = vny;
        row[4] = cell; row[5] = h2;  row[6] = h3;
        row[7] = x[n * 10 + 7];
        row[8] = x[n * 10 + 8];
        row[9] = x[n * 10 + 9];

        float apx = fabsf(npx), apy = fabsf(npy);
        if (apx > 1.0f) bc += logf(apx + 1e-6f);
        if (apy > 1.0f) bc += logf(apy + 1e-6f);

        int deg  = dp & 0xFFFF;
        int cdeg = dp >> 16;
        bool dead = (cell == 1.0f) && (deg < 3);
        bool cons = (cell == 0.0f) && (cdeg >= 3);
        out[OUT_KEEP + n] = (dead || cons) ? 0.0f : 1.0f;
        deadf = dead ? 1.0f : 0.0f;
        consf = cons ? 1.0f : 0.0f;
        avx = fabsf(nvx) * (1.0f / NN);
        avy = fabsf(nvy) * (1.0f / NN);
    }

    float r[5] = { avx, avy, bc, consf, deadf };
#pragma unroll
    for (int q = 0; q < 5; ++q) {
#pragma unroll
        for (int off = 32; off > 0; off >>= 1)
            r[q] += __shfl_down(r[q], off);
    }
    int lane = tid & 63, wv = tid >> 6;
    if (lane == 0) {
#pragma unroll
        for (int q = 0; q < 5; ++q) sRed[wv][q] = r[q];
    }
    __syncthreads();
    if (tid == 0) {
#pragma unroll
        for (int q = 0; q < 5; ++q) {
            float acc = sRed[0][q] + sRed[1][q] + sRed[2][q] + sRed[3][q];
            atomicAdd(&out_scalars[q], acc);
        }
    }
}

extern "C" void kernel_launch(void* const* d_in, const int* in_sizes, int n_in,
                              void* d_out, int out_size, void* d_ws, size_t ws_size,
                              hipStream_t stream) {
    const float* x      = (const float*)d_in[0];
    const int*   src    = (const int*)  d_in[1];
    const int*   dst    = (const int*)  d_in[2];
    const float* noise  = (const float*)d_in[3];
    const float* W_edge = (const float*)d_in[4];
    const float* W_src  = (const float*)d_in[5];
    const float* b1     = (const float*)d_in[6];
    const float* W_out  = (const float*)d_in[7];
    const float* b2     = (const float*)d_in[8];

    float* ws = (float*)d_ws;
    float4*   nodeinfo = (float4*)(ws + WS_NI);
    float*    s2       = ws + WS_S2;
    int*      gcur     = (int*)(ws + WS_GCUR);
    unsigned* bucket   = (unsigned*)(ws + WS_BK);
    float4*   pacc     = (float4*)(ws + WS_PACC);
    int*      pdeg     = (int*)(ws + WS_PDEG);

    float* out         = (float*)d_out;
    float* out_scalars = out + OUT_SCAL;

    k1_prep<<<196, 256, 0, stream>>>(
        x, W_edge, W_src, b1, nodeinfo, s2, gcur, out_scalars);

    k_scatter<<<SCB, 256, 0, stream>>>(src, dst, gcur, bucket);

    k_agg<<<NT * NSL, 512, 0, stream>>>(
        W_edge, W_out, nodeinfo, s2, gcur, bucket, pacc, pdeg, out_scalars);

    k_final<<<196, 256, 0, stream>>>(
        x, noise, b2, pacc, pdeg, out, out_scalars);
}